// Round 8
// baseline (293.129 us; speedup 1.0000x reference)
//
#include <hip/hip_runtime.h>

typedef short short8 __attribute__((ext_vector_type(8)));
typedef float f32x4 __attribute__((ext_vector_type(4)));

#define N_NODES 100000
#define N_A     50000
#define N_EDGES 500000
#define N_T     4
#define D_IN    128
#define HF      128
#define BCOLS   144                  // 128 ft cols + 4 el + 4 er + 8 zero pad
#define TN      (N_T * N_NODES)
#define TE      (N_T * N_EDGES)
#define NB1     ((TN + 1023) / 1024) // 391 scan blocks
#define TILE_E  (BCOLS * D_IN)       // 18432 elems = 36864 B per (t) B-tile
#define LOG2E   1.44269504088896340736f

__device__ __forceinline__ unsigned short f2b(float f) {
  unsigned int u = __float_as_uint(f);
  u += 0x7FFFu + ((u >> 16) & 1u);
  return (unsigned short)(u >> 16);
}
__device__ __forceinline__ unsigned int pk2(float lo, float hi) {
  return (unsigned int)f2b(lo) | ((unsigned int)f2b(hi) << 16);
}
__device__ __forceinline__ float blo(unsigned int u) { return __uint_as_float(u << 16); }
__device__ __forceinline__ float bhi(unsigned int u) { return __uint_as_float(u & 0xFFFF0000u); }

// K0: fused prep. Blocks 0-1: Bt[t][144][128] bf16, XOR-swizzled
// ((j*128+k) ^ ((j&7)<<3)); rows 128..135 hold W@attn_{l,r} PRE-SCALED by
// log2(e) so gather can use exp2. Blocks 2-33: WmT (permuted-k merge weights).
__global__ __launch_bounds__(256) void k_prep(const float* __restrict__ W,
    const float* __restrict__ al, const float* __restrict__ ar,
    const float* __restrict__ Wm,
    unsigned short* __restrict__ Bt, unsigned short* __restrict__ WmT)
{
  if (blockIdx.x < 2) {
    int idx = blockIdx.x * 256 + threadIdx.x;
    int t = idx >> 7, k = idx & 127;
    const float* Wr = W + ((size_t)t * D_IN + k) * HF;
    unsigned short* o = Bt + (size_t)t * TILE_E;
    for (int j = 0; j < HF; ++j)
      o[(j * D_IN + k) ^ ((j & 7) << 3)] = f2b(Wr[j]);
    for (int h = 0; h < 4; ++h) {
      float sl = 0.f, sr = 0.f;
      const float* alh = al + (t * 4 + h) * 32;
      const float* arh = ar + (t * 4 + h) * 32;
      for (int f = 0; f < 32; ++f) { float w = Wr[h * 32 + f]; sl += w * alh[f]; sr += w * arh[f]; }
      int jl = 128 + h, jr = 132 + h;
      o[(jl * D_IN + k) ^ ((jl & 7) << 3)] = f2b(sl * LOG2E);
      o[(jr * D_IN + k) ^ ((jr & 7) << 3)] = f2b(sr * LOG2E);
    }
    for (int j = 136; j < 144; ++j)
      o[(j * D_IN + k) ^ ((j & 7) << 3)] = 0;
  } else {
    int idx = (blockIdx.x - 2) * 256 + threadIdx.x;
    int kidx = idx >> 5, j = idx & 31;
    int slot = kidx >> 7, p = kidx & 127;
    int col = (p & 7) * 16 + (p >> 3);
    WmT[j * 256 + kidx] = f2b(Wm[(slot * 128 + col) * 32 + j]);
  }
}

// K1: projection GEMM. Block = 128 rows (8 waves x 16 rows), grid 782.
// LDS 36.8 KB + <=64 VGPR -> 4 blocks/CU x 8 waves = 32 waves/CU.
// ALL waves stay alive through staging + barriers (last block has OOB rows:
// A-loads clamped, stores guarded). ft written in permuted layout.
__global__ __launch_bounds__(512, 8) void k_proj(const float* __restrict__ feat,
    const unsigned short* __restrict__ Btg,
    unsigned short* __restrict__ ftg,
    float* __restrict__ elg, float* __restrict__ erg)
{
  __shared__ __align__(16) unsigned short Bs[TILE_E];      // 36.8 KB
  const int tid = threadIdx.x;
  const int wave = tid >> 6, lane = tid & 63;
  const int l15 = lane & 15, g = lane >> 4;
  const int wrow0 = blockIdx.x * 128 + wave * 16;

  // A fragments: row = wrow0 + l15 (clamped for the tail block)
  short8 a[4];
  {
    int row = wrow0 + l15;
    const float* fr = feat + (size_t)(row < N_NODES ? row : N_NODES - 1) * D_IN;
#pragma unroll
    for (int kt = 0; kt < 4; ++kt) {
      float4 v0 = *(const float4*)(fr + kt * 32 + g * 8);
      float4 v1 = *(const float4*)(fr + kt * 32 + g * 8 + 4);
      short8 s;
      s[0] = (short)f2b(v0.x); s[1] = (short)f2b(v0.y);
      s[2] = (short)f2b(v0.z); s[3] = (short)f2b(v0.w);
      s[4] = (short)f2b(v1.x); s[5] = (short)f2b(v1.y);
      s[6] = (short)f2b(v1.z); s[7] = (short)f2b(v1.w);
      a[kt] = s;
    }
  }

  for (int t = 0; t < N_T; ++t) {
    if (t > 0) __syncthreads();                            // Bs reads of t-1 done
    {                                                      // stage B tile (linear copy)
      const uint4* src = (const uint4*)(Btg + (size_t)t * TILE_E);
      uint4* dstv = (uint4*)Bs;
      for (int i = tid; i < 2304; i += 512)
        dstv[i] = src[i];
    }
    __syncthreads();

    f32x4 acc[8];
#pragma unroll
    for (int ct = 0; ct < 8; ++ct) {
      f32x4 c = {0.f, 0.f, 0.f, 0.f};
#pragma unroll
      for (int kt = 0; kt < 4; ++kt) {
        int row = ct * 16 + l15;
        int boff = (row * 256 + kt * 64 + g * 16) ^ ((l15 & 7) << 4);
        short8 b = *(const short8*)((const char*)Bs + boff);
        c = __builtin_amdgcn_mfma_f32_16x16x32_bf16(a[kt], b, c, 0, 0, 0);
      }
      acc[ct] = c;
    }
    {                                                      // ct=8: el/er columns
      f32x4 c8 = {0.f, 0.f, 0.f, 0.f};
#pragma unroll
      for (int kt = 0; kt < 4; ++kt) {
        int row = 128 + l15;
        int boff = (row * 256 + kt * 64 + g * 16) ^ ((l15 & 7) << 4);
        short8 b = *(const short8*)((const char*)Bs + boff);
        c8 = __builtin_amdgcn_mfma_f32_16x16x32_bf16(a[kt], b, c8, 0, 0, 0);
      }
      if (l15 < 8) {
#pragma unroll
        for (int r = 0; r < 4; ++r) {
          int row = wrow0 + g * 4 + r;
          if (row < N_NODES) {
            float v = c8[r];
            if (l15 < 4) elg[((size_t)t * N_NODES + row) * 4 + l15] = v;
            else         erg[((size_t)t * N_NODES + row) * 4 + (l15 - 4)] = v;
          }
        }
      }
    }
    // direct permuted ft store: row-position p = l15*8 + ct
#pragma unroll
    for (int r = 0; r < 4; ++r) {
      int row = wrow0 + g * 4 + r;
      if (row < N_NODES) {
        uint4 o;
        o.x = pk2(acc[0][r], acc[1][r]);
        o.y = pk2(acc[2][r], acc[3][r]);
        o.z = pk2(acc[4][r], acc[5][r]);
        o.w = pk2(acc[6][r], acc[7][r]);
        *(uint4*)(ftg + ((size_t)t * N_NODES + row) * HF + l15 * 8) = o;
      }
    }
  }
}

// K2: histogram of kept edges by (t,dst) + per-edge within-bucket rank
__global__ __launch_bounds__(256) void k_hist(const int* __restrict__ dst,
    int* __restrict__ cnt, int* __restrict__ rank) {
  int idx = blockIdx.x * 256 + threadIdx.x;
  if (idx >= TE) return;
  int t = idx / N_EDGES;
  int d = dst[idx];
  bool keep = (t < 2) ? (d < N_A) : (d >= N_A);
  if (keep) rank[idx] = atomicAdd(&cnt[t * N_NODES + d], 1);
}

__global__ __launch_bounds__(256) void k_scan1(const int* __restrict__ cnt,
    int* __restrict__ ofs, int* __restrict__ bsum) {
  __shared__ int ts[256];
  int b = blockIdx.x, t = threadIdx.x;
  int base = b * 1024 + t * 4;
  int v0 = 0, v1 = 0, v2 = 0, v3 = 0;
  if (base + 0 < TN) v0 = cnt[base + 0];
  if (base + 1 < TN) v1 = cnt[base + 1];
  if (base + 2 < TN) v2 = cnt[base + 2];
  if (base + 3 < TN) v3 = cnt[base + 3];
  int s = v0 + v1 + v2 + v3;
  ts[t] = s;
  __syncthreads();
  for (int o = 1; o < 256; o <<= 1) {
    int x = (t >= o) ? ts[t - o] : 0;
    __syncthreads();
    ts[t] += x;
    __syncthreads();
  }
  int run = ts[t] - s;
  if (base + 0 < TN) ofs[base + 0] = run; run += v0;
  if (base + 1 < TN) ofs[base + 1] = run; run += v1;
  if (base + 2 < TN) ofs[base + 2] = run; run += v2;
  if (base + 3 < TN) ofs[base + 3] = run;
  if (t == 255) bsum[b] = ts[255];
}

__global__ __launch_bounds__(512) void k_scan2(int* __restrict__ bsum) {
  __shared__ int ts[512];
  int t = threadIdx.x;
  int v = (t < NB1) ? bsum[t] : 0;
  ts[t] = v;
  __syncthreads();
  for (int o = 1; o < 512; o <<= 1) {
    int x = (t >= o) ? ts[t - o] : 0;
    __syncthreads();
    ts[t] += x;
    __syncthreads();
  }
  if (t < NB1) bsum[t] = ts[t] - v;
}

// K3: slim scatter: 4 B record = src ft-row index; position from ofs+bsum+rank.
__global__ __launch_bounds__(256) void k_scatter(const int* __restrict__ src, const int* __restrict__ dst,
    const int* __restrict__ ofs, const int* __restrict__ bsum, const int* __restrict__ rank,
    int* __restrict__ bkt) {
  int idx = blockIdx.x * 256 + threadIdx.x;
  if (idx >= TE) return;
  int t = idx / N_EDGES;
  int d = dst[idx];
  bool keep = (t < 2) ? (d < N_A) : (d >= N_A);
  if (!keep) return;
  int key = t * N_NODES + d;
  int p = ofs[key] + bsum[key >> 10] + rank[idx];
  bkt[p] = t * N_NODES + src[idx];
}

// K4: gather. 8 pairs per wave, 8 lanes per pair (32 B of ft row per lane).
// Per edge: 4 B record (broadcast) + 16 B el (broadcast) + 2x16 B ft; weights
// w[h] = exp2(fmax(s, 0.2s)) with s = el'+er' pre-scaled by log2e at prep.
// 2x unrolled. No cross-lane reduction; coalesced group store.
__global__ __launch_bounds__(256) void k_gather(const int* __restrict__ bkt,
    const int* __restrict__ ofs, const int* __restrict__ cnt, const int* __restrict__ bsum,
    const float* __restrict__ elg, const float* __restrict__ erg,
    const uint4* __restrict__ ftu, uint4* __restrict__ aggb)
{
  int wid = blockIdx.x * 4 + (threadIdx.x >> 6);
  int lane = threadIdx.x & 63;
  int g8 = lane >> 3, l7 = lane & 7;
  int pid = wid * 8 + g8;                      // pair id = node*2 + slot
  int n = pid >> 1, slot = pid & 1;
  int t = slot + ((n >= N_A) ? 2 : 0);
  int key = t * N_NODES + n;
  int base = ofs[key] + bsum[key >> 10];
  int c = cnt[key];
  float4 er4 = *(const float4*)(erg + (size_t)key * 4);
  float a00 = 0.f, a01 = 0.f, a02 = 0.f, a03 = 0.f, a04 = 0.f, a05 = 0.f, a06 = 0.f, a07 = 0.f;
  float a10 = 0.f, a11 = 0.f, a12 = 0.f, a13 = 0.f, a14 = 0.f, a15 = 0.f, a16 = 0.f, a17 = 0.f;
  float d0 = 0.f, d1 = 0.f, d2 = 0.f, d3 = 0.f;
  int qb = l7 * 2;
  int i = 0;
  for (; i + 1 < c; i += 2) {
    int s0 = bkt[base + i];
    int s1 = bkt[base + i + 1];
    float4 el0 = *(const float4*)(elg + (size_t)s0 * 4);
    float4 el1 = *(const float4*)(elg + (size_t)s1 * 4);
    uint4 u0a = ftu[(size_t)s0 * 16 + qb];
    uint4 u0b = ftu[(size_t)s0 * 16 + qb + 1];
    uint4 u1a = ftu[(size_t)s1 * 16 + qb];
    uint4 u1b = ftu[(size_t)s1 * 16 + qb + 1];
    float s, w0, w1, w2, w3;
    s = el0.x + er4.x; w0 = exp2f(fmaxf(s, 0.2f * s));
    s = el0.y + er4.y; w1 = exp2f(fmaxf(s, 0.2f * s));
    s = el0.z + er4.z; w2 = exp2f(fmaxf(s, 0.2f * s));
    s = el0.w + er4.w; w3 = exp2f(fmaxf(s, 0.2f * s));
    d0 += w0; d1 += w1; d2 += w2; d3 += w3;
    a00 += w0 * blo(u0a.x); a01 += w0 * bhi(u0a.x);
    a02 += w1 * blo(u0a.y); a03 += w1 * bhi(u0a.y);
    a04 += w2 * blo(u0a.z); a05 += w2 * bhi(u0a.z);
    a06 += w3 * blo(u0a.w); a07 += w3 * bhi(u0a.w);
    a10 += w0 * blo(u0b.x); a11 += w0 * bhi(u0b.x);
    a12 += w1 * blo(u0b.y); a13 += w1 * bhi(u0b.y);
    a14 += w2 * blo(u0b.z); a15 += w2 * bhi(u0b.z);
    a16 += w3 * blo(u0b.w); a17 += w3 * bhi(u0b.w);
    s = el1.x + er4.x; w0 = exp2f(fmaxf(s, 0.2f * s));
    s = el1.y + er4.y; w1 = exp2f(fmaxf(s, 0.2f * s));
    s = el1.z + er4.z; w2 = exp2f(fmaxf(s, 0.2f * s));
    s = el1.w + er4.w; w3 = exp2f(fmaxf(s, 0.2f * s));
    d0 += w0; d1 += w1; d2 += w2; d3 += w3;
    a00 += w0 * blo(u1a.x); a01 += w0 * bhi(u1a.x);
    a02 += w1 * blo(u1a.y); a03 += w1 * bhi(u1a.y);
    a04 += w2 * blo(u1a.z); a05 += w2 * bhi(u1a.z);
    a06 += w3 * blo(u1a.w); a07 += w3 * bhi(u1a.w);
    a10 += w0 * blo(u1b.x); a11 += w0 * bhi(u1b.x);
    a12 += w1 * blo(u1b.y); a13 += w1 * bhi(u1b.y);
    a14 += w2 * blo(u1b.z); a15 += w2 * bhi(u1b.z);
    a16 += w3 * blo(u1b.w); a17 += w3 * bhi(u1b.w);
  }
  if (i < c) {
    int s0 = bkt[base + i];
    float4 el0 = *(const float4*)(elg + (size_t)s0 * 4);
    uint4 u0a = ftu[(size_t)s0 * 16 + qb];
    uint4 u0b = ftu[(size_t)s0 * 16 + qb + 1];
    float s, w0, w1, w2, w3;
    s = el0.x + er4.x; w0 = exp2f(fmaxf(s, 0.2f * s));
    s = el0.y + er4.y; w1 = exp2f(fmaxf(s, 0.2f * s));
    s = el0.z + er4.z; w2 = exp2f(fmaxf(s, 0.2f * s));
    s = el0.w + er4.w; w3 = exp2f(fmaxf(s, 0.2f * s));
    d0 += w0; d1 += w1; d2 += w2; d3 += w3;
    a00 += w0 * blo(u0a.x); a01 += w0 * bhi(u0a.x);
    a02 += w1 * blo(u0a.y); a03 += w1 * bhi(u0a.y);
    a04 += w2 * blo(u0a.z); a05 += w2 * bhi(u0a.z);
    a06 += w3 * blo(u0a.w); a07 += w3 * bhi(u0a.w);
    a10 += w0 * blo(u0b.x); a11 += w0 * bhi(u0b.x);
    a12 += w1 * blo(u0b.y); a13 += w1 * bhi(u0b.y);
    a14 += w2 * blo(u0b.z); a15 += w2 * bhi(u0b.z);
    a16 += w3 * blo(u0b.w); a17 += w3 * bhi(u0b.w);
  }
  float i0 = (c > 0) ? 1.f / d0 : 0.f;
  float i1 = (c > 0) ? 1.f / d1 : 0.f;
  float i2 = (c > 0) ? 1.f / d2 : 0.f;
  float i3 = (c > 0) ? 1.f / d3 : 0.f;
  uint4 oA, oB;
  oA.x = pk2(a00 * i0, a01 * i0);
  oA.y = pk2(a02 * i1, a03 * i1);
  oA.z = pk2(a04 * i2, a05 * i2);
  oA.w = pk2(a06 * i3, a07 * i3);
  oB.x = pk2(a10 * i0, a11 * i0);
  oB.y = pk2(a12 * i1, a13 * i1);
  oB.z = pk2(a14 * i2, a15 * i2);
  oB.w = pk2(a16 * i3, a17 * i3);
  size_t ob = (size_t)n * 32 + slot * 16 + qb;
  aggb[ob] = oA;
  aggb[ob + 1] = oB;
}

// K5: merge GEMM via MFMA. 64 nodes/block, out = agg(bf16, permuted-k) @ WmT + bm.
__global__ __launch_bounds__(256) void k_merge(const unsigned short* __restrict__ aggb,
    const unsigned short* __restrict__ WmT, const float* __restrict__ bm,
    float* __restrict__ out)
{
  __shared__ __align__(16) unsigned short Al[64 * 264];
  __shared__ __align__(16) unsigned short Bl[32 * 264];
  int n0 = blockIdx.x * 64;
  int tid = threadIdx.x;
  const uint4* asrc = (const uint4*)(aggb + (size_t)n0 * 256);
  for (int i = tid; i < 2048; i += 256) {
    int r = i >> 5, c = i & 31;
    *(uint4*)&Al[r * 264 + c * 8] = asrc[r * 32 + c];
  }
  for (int i = tid; i < 1024; i += 256) {
    int r = i >> 5, c = i & 31;
    *(uint4*)&Bl[r * 264 + c * 8] = ((const uint4*)WmT)[r * 32 + c];
  }
  __syncthreads();
  int wave = tid >> 6, lane = tid & 63;
  int l15 = lane & 15, lk = (lane >> 4) * 8;
  short8 a[8];
#pragma unroll
  for (int kt = 0; kt < 8; ++kt)
    a[kt] = *(const short8*)&Al[(wave * 16 + l15) * 264 + kt * 32 + lk];
  f32x4 acc0 = {0.f, 0.f, 0.f, 0.f}, acc1 = {0.f, 0.f, 0.f, 0.f};
#pragma unroll
  for (int kt = 0; kt < 8; ++kt) {
    short8 b0 = *(const short8*)&Bl[l15 * 264 + kt * 32 + lk];
    short8 b1 = *(const short8*)&Bl[(16 + l15) * 264 + kt * 32 + lk];
    acc0 = __builtin_amdgcn_mfma_f32_16x16x32_bf16(a[kt], b0, acc0, 0, 0, 0);
    acc1 = __builtin_amdgcn_mfma_f32_16x16x32_bf16(a[kt], b1, acc1, 0, 0, 0);
  }
  float bm0 = bm[l15], bm1 = bm[16 + l15];
#pragma unroll
  for (int r = 0; r < 4; ++r) {
    int row = n0 + wave * 16 + (lane >> 4) * 4 + r;
    if (row < N_NODES) {
      out[(size_t)row * 32 + l15] = acc0[r] + bm0;
      out[(size_t)row * 32 + 16 + l15] = acc1[r] + bm1;
    }
  }
}

extern "C" void kernel_launch(void* const* d_in, const int* in_sizes, int n_in,
                              void* d_out, int out_size, void* d_ws, size_t ws_size,
                              hipStream_t stream)
{
  const float* feat = (const float*)d_in[0];
  const int*   src  = (const int*)d_in[1];
  const int*   dst  = (const int*)d_in[2];
  const float* W    = (const float*)d_in[4];
  const float* al   = (const float*)d_in[5];
  const float* ar   = (const float*)d_in[6];
  const float* Wm   = (const float*)d_in[7];
  const float* bm   = (const float*)d_in[8];
  float* out = (float*)d_out;
  (void)in_sizes; (void)n_in; (void)out_size; (void)ws_size;

  char* w = (char*)d_ws;
  size_t o = 0;
  auto take = [&](size_t bytes) -> void* {
    void* p = w + o;
    o += (bytes + 255) & ~(size_t)255;
    return p;
  };
  unsigned short* Btg = (unsigned short*)take((size_t)N_T * TILE_E * 2);         // 147 KB
  unsigned short* WmT = (unsigned short*)take((size_t)32 * 256 * 2);             // 16 KB
  unsigned short* ftg = (unsigned short*)take((size_t)N_T * N_NODES * HF * 2);   // 102.4 MB
  float* elg   = (float*)take((size_t)N_T * N_NODES * 4 * 4);                    // 6.4 MB
  float* erg   = (float*)take((size_t)N_T * N_NODES * 4 * 4);                    // 6.4 MB
  int*   cntb  = (int*)take((size_t)TN * 4);                                     // 1.6 MB
  int*   ofs   = (int*)take((size_t)TN * 4);
  int*   bsum  = (int*)take(4096);
  int*   rank  = (int*)take((size_t)TE * 4);                                     // 8 MB
  int*   bkt   = (int*)take((size_t)TE * 4);                                     // 8 MB
  unsigned short* aggb = (unsigned short*)take((size_t)(N_NODES + 64) * 256 * 2);// 51.2 MB

  hipMemsetAsync(cntb, 0, (size_t)TN * 4, stream);

  k_prep<<<34, 256, 0, stream>>>(W, al, ar, Wm, Btg, WmT);
  k_proj<<<782, 512, 0, stream>>>(feat, Btg, ftg, elg, erg);
  k_hist<<<(TE + 255) / 256, 256, 0, stream>>>(dst, cntb, rank);
  k_scan1<<<NB1, 256, 0, stream>>>(cntb, ofs, bsum);
  k_scan2<<<1, 512, 0, stream>>>(bsum);
  k_scatter<<<(TE + 255) / 256, 256, 0, stream>>>(src, dst, ofs, bsum, rank, bkt);
  k_gather<<<6250, 256, 0, stream>>>(bkt, ofs, cntb, bsum, elg, erg, (const uint4*)ftg, (uint4*)aggb);
  k_merge<<<1563, 256, 0, stream>>>(aggb, WmT, bm, out);
}

// Round 9
// 203.858 us; speedup vs baseline: 1.4379x; 1.4379x over previous
//
#include <hip/hip_runtime.h>

typedef short short8 __attribute__((ext_vector_type(8)));
typedef float f32x4 __attribute__((ext_vector_type(4)));

#define N_NODES 100000
#define N_A     50000
#define N_EDGES 500000
#define N_T     4
#define D_IN    128
#define HF      128
#define BCOLS   144                  // 128 ft cols + 4 el + 4 er + 8 zero pad
#define TN      (N_T * N_NODES)
#define TE      (N_T * N_EDGES)
#define NB1     ((TN + 1023) / 1024) // 391 scan blocks
#define TILE_E  (BCOLS * D_IN)       // 18432 elems = 36864 B per (t) B-tile
#define LOG2E   1.44269504088896340736f

__device__ __forceinline__ unsigned short f2b(float f) {
  unsigned int u = __float_as_uint(f);
  u += 0x7FFFu + ((u >> 16) & 1u);
  return (unsigned short)(u >> 16);
}
__device__ __forceinline__ unsigned int pk2(float lo, float hi) {
  return (unsigned int)f2b(lo) | ((unsigned int)f2b(hi) << 16);
}
__device__ __forceinline__ float blo(unsigned int u) { return __uint_as_float(u << 16); }
__device__ __forceinline__ float bhi(unsigned int u) { return __uint_as_float(u & 0xFFFF0000u); }

// K0: fused prep. Blocks 0-1: Bt[t][144][128] bf16, XOR-swizzled
// ((j*128+k) ^ ((j&7)<<3)); rows 128..135 hold W@attn_{l,r} PRE-SCALED by
// log2(e) so gather can use exp2. Blocks 2-33: WmT (permuted-k merge weights).
__global__ __launch_bounds__(256) void k_prep(const float* __restrict__ W,
    const float* __restrict__ al, const float* __restrict__ ar,
    const float* __restrict__ Wm,
    unsigned short* __restrict__ Bt, unsigned short* __restrict__ WmT)
{
  if (blockIdx.x < 2) {
    int idx = blockIdx.x * 256 + threadIdx.x;
    int t = idx >> 7, k = idx & 127;
    const float* Wr = W + ((size_t)t * D_IN + k) * HF;
    unsigned short* o = Bt + (size_t)t * TILE_E;
    for (int j = 0; j < HF; ++j)
      o[(j * D_IN + k) ^ ((j & 7) << 3)] = f2b(Wr[j]);
    for (int h = 0; h < 4; ++h) {
      float sl = 0.f, sr = 0.f;
      const float* alh = al + (t * 4 + h) * 32;
      const float* arh = ar + (t * 4 + h) * 32;
      for (int f = 0; f < 32; ++f) { float w = Wr[h * 32 + f]; sl += w * alh[f]; sr += w * arh[f]; }
      int jl = 128 + h, jr = 132 + h;
      o[(jl * D_IN + k) ^ ((jl & 7) << 3)] = f2b(sl * LOG2E);
      o[(jr * D_IN + k) ^ ((jr & 7) << 3)] = f2b(sr * LOG2E);
    }
    for (int j = 136; j < 144; ++j)
      o[(j * D_IN + k) ^ ((j & 7) << 3)] = 0;
  } else {
    int idx = (blockIdx.x - 2) * 256 + threadIdx.x;
    int kidx = idx >> 5, j = idx & 31;
    int slot = kidx >> 7, p = kidx & 127;
    int col = (p & 7) * 16 + (p >> 3);
    WmT[j * 256 + kidx] = f2b(Wm[(slot * 128 + col) * 32 + j]);
  }
}

// K1: projection GEMM (round-6 proven shape). Block = 64 rows (4 waves x 16),
// grid 1563, launch_bounds(256,4) -> 52 VGPR, no spill, 4 blocks/CU.
// A-frags from global feat (f32->bf16 in reg, loaded once). B staged in LDS
// per t (pre-swizzled -> linear copy), read via swizzled ds_read_b128.
// ft written DIRECTLY from accumulators in permuted layout (no transpose).
__global__ __launch_bounds__(256, 4) void k_proj(const float* __restrict__ feat,
    const unsigned short* __restrict__ Btg,
    unsigned short* __restrict__ ftg,
    float* __restrict__ elg, float* __restrict__ erg)
{
  __shared__ __align__(16) unsigned short Bs[TILE_E];      // 36.8 KB -> 4 blocks/CU
  const int tid = threadIdx.x;
  const int wave = tid >> 6, lane = tid & 63;
  const int l15 = lane & 15, g = lane >> 4;
  const int wrow0 = blockIdx.x * 64 + wave * 16;

  // A fragments: row = wrow0 + l15 (clamped; stores guarded)
  short8 a[4];
  {
    int row = wrow0 + l15;
    const float* fr = feat + (size_t)(row < N_NODES ? row : N_NODES - 1) * D_IN;
#pragma unroll
    for (int kt = 0; kt < 4; ++kt) {
      float4 v0 = *(const float4*)(fr + kt * 32 + g * 8);
      float4 v1 = *(const float4*)(fr + kt * 32 + g * 8 + 4);
      short8 s;
      s[0] = (short)f2b(v0.x); s[1] = (short)f2b(v0.y);
      s[2] = (short)f2b(v0.z); s[3] = (short)f2b(v0.w);
      s[4] = (short)f2b(v1.x); s[5] = (short)f2b(v1.y);
      s[6] = (short)f2b(v1.z); s[7] = (short)f2b(v1.w);
      a[kt] = s;
    }
  }

  for (int t = 0; t < N_T; ++t) {
    if (t > 0) __syncthreads();                            // Bs reads of t-1 done
    {                                                      // stage B tile (linear copy)
      const uint4* src = (const uint4*)(Btg + (size_t)t * TILE_E);
      uint4* dstv = (uint4*)Bs;
#pragma unroll
      for (int i = 0; i < 9; ++i)
        dstv[i * 256 + tid] = src[i * 256 + tid];
    }
    __syncthreads();

    f32x4 acc[8];
#pragma unroll
    for (int ct = 0; ct < 8; ++ct) {
      f32x4 c = {0.f, 0.f, 0.f, 0.f};
#pragma unroll
      for (int kt = 0; kt < 4; ++kt) {
        int row = ct * 16 + l15;
        int boff = (row * 256 + kt * 64 + g * 16) ^ ((l15 & 7) << 4);
        short8 b = *(const short8*)((const char*)Bs + boff);
        c = __builtin_amdgcn_mfma_f32_16x16x32_bf16(a[kt], b, c, 0, 0, 0);
      }
      acc[ct] = c;
    }
    {                                                      // ct=8: el/er columns
      f32x4 c8 = {0.f, 0.f, 0.f, 0.f};
#pragma unroll
      for (int kt = 0; kt < 4; ++kt) {
        int row = 128 + l15;
        int boff = (row * 256 + kt * 64 + g * 16) ^ ((l15 & 7) << 4);
        short8 b = *(const short8*)((const char*)Bs + boff);
        c8 = __builtin_amdgcn_mfma_f32_16x16x32_bf16(a[kt], b, c8, 0, 0, 0);
      }
      if (l15 < 8) {
#pragma unroll
        for (int r = 0; r < 4; ++r) {
          int row = wrow0 + g * 4 + r;
          if (row < N_NODES) {
            float v = c8[r];
            if (l15 < 4) elg[((size_t)t * N_NODES + row) * 4 + l15] = v;
            else         erg[((size_t)t * N_NODES + row) * 4 + (l15 - 4)] = v;
          }
        }
      }
    }
    // direct permuted ft store: row-position p = l15*8 + ct
#pragma unroll
    for (int r = 0; r < 4; ++r) {
      int row = wrow0 + g * 4 + r;
      if (row < N_NODES) {
        uint4 o;
        o.x = pk2(acc[0][r], acc[1][r]);
        o.y = pk2(acc[2][r], acc[3][r]);
        o.z = pk2(acc[4][r], acc[5][r]);
        o.w = pk2(acc[6][r], acc[7][r]);
        *(uint4*)(ftg + ((size_t)t * N_NODES + row) * HF + l15 * 8) = o;
      }
    }
  }
}

// K2: histogram of kept edges by (t,dst) + per-edge within-bucket rank
__global__ __launch_bounds__(256) void k_hist(const int* __restrict__ dst,
    int* __restrict__ cnt, int* __restrict__ rank) {
  int idx = blockIdx.x * 256 + threadIdx.x;
  if (idx >= TE) return;
  int t = idx / N_EDGES;
  int d = dst[idx];
  bool keep = (t < 2) ? (d < N_A) : (d >= N_A);
  if (keep) rank[idx] = atomicAdd(&cnt[t * N_NODES + d], 1);
}

__global__ __launch_bounds__(256) void k_scan1(const int* __restrict__ cnt,
    int* __restrict__ ofs, int* __restrict__ bsum) {
  __shared__ int ts[256];
  int b = blockIdx.x, t = threadIdx.x;
  int base = b * 1024 + t * 4;
  int v0 = 0, v1 = 0, v2 = 0, v3 = 0;
  if (base + 0 < TN) v0 = cnt[base + 0];
  if (base + 1 < TN) v1 = cnt[base + 1];
  if (base + 2 < TN) v2 = cnt[base + 2];
  if (base + 3 < TN) v3 = cnt[base + 3];
  int s = v0 + v1 + v2 + v3;
  ts[t] = s;
  __syncthreads();
  for (int o = 1; o < 256; o <<= 1) {
    int x = (t >= o) ? ts[t - o] : 0;
    __syncthreads();
    ts[t] += x;
    __syncthreads();
  }
  int run = ts[t] - s;
  if (base + 0 < TN) ofs[base + 0] = run; run += v0;
  if (base + 1 < TN) ofs[base + 1] = run; run += v1;
  if (base + 2 < TN) ofs[base + 2] = run; run += v2;
  if (base + 3 < TN) ofs[base + 3] = run;
  if (t == 255) bsum[b] = ts[255];
}

__global__ __launch_bounds__(512) void k_scan2(int* __restrict__ bsum) {
  __shared__ int ts[512];
  int t = threadIdx.x;
  int v = (t < NB1) ? bsum[t] : 0;
  ts[t] = v;
  __syncthreads();
  for (int o = 1; o < 512; o <<= 1) {
    int x = (t >= o) ? ts[t - o] : 0;
    __syncthreads();
    ts[t] += x;
    __syncthreads();
  }
  if (t < NB1) bsum[t] = ts[t] - v;
}

// K3: slim scatter: 4 B record = src ft-row index; position from ofs+bsum+rank.
__global__ __launch_bounds__(256) void k_scatter(const int* __restrict__ src, const int* __restrict__ dst,
    const int* __restrict__ ofs, const int* __restrict__ bsum, const int* __restrict__ rank,
    int* __restrict__ bkt) {
  int idx = blockIdx.x * 256 + threadIdx.x;
  if (idx >= TE) return;
  int t = idx / N_EDGES;
  int d = dst[idx];
  bool keep = (t < 2) ? (d < N_A) : (d >= N_A);
  if (!keep) return;
  int key = t * N_NODES + d;
  int p = ofs[key] + bsum[key >> 10] + rank[idx];
  bkt[p] = t * N_NODES + src[idx];
}

// K4: gather. 8 pairs per wave, 8 lanes per pair (32 B of ft row per lane).
// Per edge: 4 B record (broadcast) + 16 B el (broadcast) + 2x16 B ft; weights
// w[h] = exp2(fmax(s, 0.2s)) with s = el'+er' pre-scaled by log2e at prep.
// 2x unrolled. No cross-lane reduction; coalesced group store.
__global__ __launch_bounds__(256) void k_gather(const int* __restrict__ bkt,
    const int* __restrict__ ofs, const int* __restrict__ cnt, const int* __restrict__ bsum,
    const float* __restrict__ elg, const float* __restrict__ erg,
    const uint4* __restrict__ ftu, uint4* __restrict__ aggb)
{
  int wid = blockIdx.x * 4 + (threadIdx.x >> 6);
  int lane = threadIdx.x & 63;
  int g8 = lane >> 3, l7 = lane & 7;
  int pid = wid * 8 + g8;                      // pair id = node*2 + slot
  int n = pid >> 1, slot = pid & 1;
  int t = slot + ((n >= N_A) ? 2 : 0);
  int key = t * N_NODES + n;
  int base = ofs[key] + bsum[key >> 10];
  int c = cnt[key];
  float4 er4 = *(const float4*)(erg + (size_t)key * 4);
  float a00 = 0.f, a01 = 0.f, a02 = 0.f, a03 = 0.f, a04 = 0.f, a05 = 0.f, a06 = 0.f, a07 = 0.f;
  float a10 = 0.f, a11 = 0.f, a12 = 0.f, a13 = 0.f, a14 = 0.f, a15 = 0.f, a16 = 0.f, a17 = 0.f;
  float d0 = 0.f, d1 = 0.f, d2 = 0.f, d3 = 0.f;
  int qb = l7 * 2;
  int i = 0;
  for (; i + 1 < c; i += 2) {
    int s0 = bkt[base + i];
    int s1 = bkt[base + i + 1];
    float4 el0 = *(const float4*)(elg + (size_t)s0 * 4);
    float4 el1 = *(const float4*)(elg + (size_t)s1 * 4);
    uint4 u0a = ftu[(size_t)s0 * 16 + qb];
    uint4 u0b = ftu[(size_t)s0 * 16 + qb + 1];
    uint4 u1a = ftu[(size_t)s1 * 16 + qb];
    uint4 u1b = ftu[(size_t)s1 * 16 + qb + 1];
    float s, w0, w1, w2, w3;
    s = el0.x + er4.x; w0 = exp2f(fmaxf(s, 0.2f * s));
    s = el0.y + er4.y; w1 = exp2f(fmaxf(s, 0.2f * s));
    s = el0.z + er4.z; w2 = exp2f(fmaxf(s, 0.2f * s));
    s = el0.w + er4.w; w3 = exp2f(fmaxf(s, 0.2f * s));
    d0 += w0; d1 += w1; d2 += w2; d3 += w3;
    a00 += w0 * blo(u0a.x); a01 += w0 * bhi(u0a.x);
    a02 += w1 * blo(u0a.y); a03 += w1 * bhi(u0a.y);
    a04 += w2 * blo(u0a.z); a05 += w2 * bhi(u0a.z);
    a06 += w3 * blo(u0a.w); a07 += w3 * bhi(u0a.w);
    a10 += w0 * blo(u0b.x); a11 += w0 * bhi(u0b.x);
    a12 += w1 * blo(u0b.y); a13 += w1 * bhi(u0b.y);
    a14 += w2 * blo(u0b.z); a15 += w2 * bhi(u0b.z);
    a16 += w3 * blo(u0b.w); a17 += w3 * bhi(u0b.w);
    s = el1.x + er4.x; w0 = exp2f(fmaxf(s, 0.2f * s));
    s = el1.y + er4.y; w1 = exp2f(fmaxf(s, 0.2f * s));
    s = el1.z + er4.z; w2 = exp2f(fmaxf(s, 0.2f * s));
    s = el1.w + er4.w; w3 = exp2f(fmaxf(s, 0.2f * s));
    d0 += w0; d1 += w1; d2 += w2; d3 += w3;
    a00 += w0 * blo(u1a.x); a01 += w0 * bhi(u1a.x);
    a02 += w1 * blo(u1a.y); a03 += w1 * bhi(u1a.y);
    a04 += w2 * blo(u1a.z); a05 += w2 * bhi(u1a.z);
    a06 += w3 * blo(u1a.w); a07 += w3 * bhi(u1a.w);
    a10 += w0 * blo(u1b.x); a11 += w0 * bhi(u1b.x);
    a12 += w1 * blo(u1b.y); a13 += w1 * bhi(u1b.y);
    a14 += w2 * blo(u1b.z); a15 += w2 * bhi(u1b.z);
    a16 += w3 * blo(u1b.w); a17 += w3 * bhi(u1b.w);
  }
  if (i < c) {
    int s0 = bkt[base + i];
    float4 el0 = *(const float4*)(elg + (size_t)s0 * 4);
    uint4 u0a = ftu[(size_t)s0 * 16 + qb];
    uint4 u0b = ftu[(size_t)s0 * 16 + qb + 1];
    float s, w0, w1, w2, w3;
    s = el0.x + er4.x; w0 = exp2f(fmaxf(s, 0.2f * s));
    s = el0.y + er4.y; w1 = exp2f(fmaxf(s, 0.2f * s));
    s = el0.z + er4.z; w2 = exp2f(fmaxf(s, 0.2f * s));
    s = el0.w + er4.w; w3 = exp2f(fmaxf(s, 0.2f * s));
    d0 += w0; d1 += w1; d2 += w2; d3 += w3;
    a00 += w0 * blo(u0a.x); a01 += w0 * bhi(u0a.x);
    a02 += w1 * blo(u0a.y); a03 += w1 * bhi(u0a.y);
    a04 += w2 * blo(u0a.z); a05 += w2 * bhi(u0a.z);
    a06 += w3 * blo(u0a.w); a07 += w3 * bhi(u0a.w);
    a10 += w0 * blo(u0b.x); a11 += w0 * bhi(u0b.x);
    a12 += w1 * blo(u0b.y); a13 += w1 * bhi(u0b.y);
    a14 += w2 * blo(u0b.z); a15 += w2 * bhi(u0b.z);
    a16 += w3 * blo(u0b.w); a17 += w3 * bhi(u0b.w);
  }
  float i0 = (c > 0) ? 1.f / d0 : 0.f;
  float i1 = (c > 0) ? 1.f / d1 : 0.f;
  float i2 = (c > 0) ? 1.f / d2 : 0.f;
  float i3 = (c > 0) ? 1.f / d3 : 0.f;
  uint4 oA, oB;
  oA.x = pk2(a00 * i0, a01 * i0);
  oA.y = pk2(a02 * i1, a03 * i1);
  oA.z = pk2(a04 * i2, a05 * i2);
  oA.w = pk2(a06 * i3, a07 * i3);
  oB.x = pk2(a10 * i0, a11 * i0);
  oB.y = pk2(a12 * i1, a13 * i1);
  oB.z = pk2(a14 * i2, a15 * i2);
  oB.w = pk2(a16 * i3, a17 * i3);
  size_t ob = (size_t)n * 32 + slot * 16 + qb;
  aggb[ob] = oA;
  aggb[ob + 1] = oB;
}

// K5: merge GEMM via MFMA. 64 nodes/block, out = agg(bf16, permuted-k) @ WmT + bm.
__global__ __launch_bounds__(256) void k_merge(const unsigned short* __restrict__ aggb,
    const unsigned short* __restrict__ WmT, const float* __restrict__ bm,
    float* __restrict__ out)
{
  __shared__ __align__(16) unsigned short Al[64 * 264];
  __shared__ __align__(16) unsigned short Bl[32 * 264];
  int n0 = blockIdx.x * 64;
  int tid = threadIdx.x;
  const uint4* asrc = (const uint4*)(aggb + (size_t)n0 * 256);
  for (int i = tid; i < 2048; i += 256) {
    int r = i >> 5, c = i & 31;
    *(uint4*)&Al[r * 264 + c * 8] = asrc[r * 32 + c];
  }
  for (int i = tid; i < 1024; i += 256) {
    int r = i >> 5, c = i & 31;
    *(uint4*)&Bl[r * 264 + c * 8] = ((const uint4*)WmT)[r * 32 + c];
  }
  __syncthreads();
  int wave = tid >> 6, lane = tid & 63;
  int l15 = lane & 15, lk = (lane >> 4) * 8;
  short8 a[8];
#pragma unroll
  for (int kt = 0; kt < 8; ++kt)
    a[kt] = *(const short8*)&Al[(wave * 16 + l15) * 264 + kt * 32 + lk];
  f32x4 acc0 = {0.f, 0.f, 0.f, 0.f}, acc1 = {0.f, 0.f, 0.f, 0.f};
#pragma unroll
  for (int kt = 0; kt < 8; ++kt) {
    short8 b0 = *(const short8*)&Bl[l15 * 264 + kt * 32 + lk];
    short8 b1 = *(const short8*)&Bl[(16 + l15) * 264 + kt * 32 + lk];
    acc0 = __builtin_amdgcn_mfma_f32_16x16x32_bf16(a[kt], b0, acc0, 0, 0, 0);
    acc1 = __builtin_amdgcn_mfma_f32_16x16x32_bf16(a[kt], b1, acc1, 0, 0, 0);
  }
  float bm0 = bm[l15], bm1 = bm[16 + l15];
#pragma unroll
  for (int r = 0; r < 4; ++r) {
    int row = n0 + wave * 16 + (lane >> 4) * 4 + r;
    if (row < N_NODES) {
      out[(size_t)row * 32 + l15] = acc0[r] + bm0;
      out[(size_t)row * 32 + 16 + l15] = acc1[r] + bm1;
    }
  }
}

extern "C" void kernel_launch(void* const* d_in, const int* in_sizes, int n_in,
                              void* d_out, int out_size, void* d_ws, size_t ws_size,
                              hipStream_t stream)
{
  const float* feat = (const float*)d_in[0];
  const int*   src  = (const int*)d_in[1];
  const int*   dst  = (const int*)d_in[2];
  const float* W    = (const float*)d_in[4];
  const float* al   = (const float*)d_in[5];
  const float* ar   = (const float*)d_in[6];
  const float* Wm   = (const float*)d_in[7];
  const float* bm   = (const float*)d_in[8];
  float* out = (float*)d_out;
  (void)in_sizes; (void)n_in; (void)out_size; (void)ws_size;

  char* w = (char*)d_ws;
  size_t o = 0;
  auto take = [&](size_t bytes) -> void* {
    void* p = w + o;
    o += (bytes + 255) & ~(size_t)255;
    return p;
  };
  unsigned short* Btg = (unsigned short*)take((size_t)N_T * TILE_E * 2);         // 147 KB
  unsigned short* WmT = (unsigned short*)take((size_t)32 * 256 * 2);             // 16 KB
  unsigned short* ftg = (unsigned short*)take((size_t)N_T * N_NODES * HF * 2);   // 102.4 MB
  float* elg   = (float*)take((size_t)N_T * N_NODES * 4 * 4);                    // 6.4 MB
  float* erg   = (float*)take((size_t)N_T * N_NODES * 4 * 4);                    // 6.4 MB
  int*   cntb  = (int*)take((size_t)TN * 4);                                     // 1.6 MB
  int*   ofs   = (int*)take((size_t)TN * 4);
  int*   bsum  = (int*)take(4096);
  int*   rank  = (int*)take((size_t)TE * 4);                                     // 8 MB
  int*   bkt   = (int*)take((size_t)TE * 4);                                     // 8 MB
  unsigned short* aggb = (unsigned short*)take((size_t)(N_NODES + 64) * 256 * 2);// 51.2 MB

  hipMemsetAsync(cntb, 0, (size_t)TN * 4, stream);

  k_prep<<<34, 256, 0, stream>>>(W, al, ar, Wm, Btg, WmT);
  k_proj<<<1563, 256, 0, stream>>>(feat, Btg, ftg, elg, erg);
  k_hist<<<(TE + 255) / 256, 256, 0, stream>>>(dst, cntb, rank);
  k_scan1<<<NB1, 256, 0, stream>>>(cntb, ofs, bsum);
  k_scan2<<<1, 512, 0, stream>>>(bsum);
  k_scatter<<<(TE + 255) / 256, 256, 0, stream>>>(src, dst, ofs, bsum, rank, bkt);
  k_gather<<<6250, 256, 0, stream>>>(bkt, ofs, cntb, bsum, elg, erg, (const uint4*)ftg, (uint4*)aggb);
  k_merge<<<1563, 256, 0, stream>>>(aggb, WmT, bm, out);
}